// Round 7
// baseline (154.577 us; speedup 1.0000x reference)
//
#include <hip/hip_runtime.h>
#include <hip/hip_bf16.h>

#define D 8196
#define H 4096
#define MLP_HID 32
#define OUT_N 130
#define ND4 2049   // D/4 float4s per W_ih row
#define NH4 1024   // H/4 float4s per W_hh row

__device__ __forceinline__ float sigmoidf_(float v) {
    return 1.0f / (1.0f + expf(-v));
}

__device__ __forceinline__ float dot4(float4 a, float4 b) {
    return a.x * b.x + a.y * b.y + a.z * b.z + a.w * b.w;
}

__device__ __forceinline__ float wave_reduce(float acc) {
    #pragma unroll
    for (int off = 32; off > 0; off >>= 1)
        acc += __shfl_down(acc, off);
    return acc;
}

// 1024 blocks x 512 threads (8 waves), 4 blocks/CU (LDS-limited) -> grid ==
// resident: exactly one dispatch round. Block owns units j0..j0+3. Wave w:
// gate g=w&3, pair p=w>>2 -> rows r0=g*H+j0+2p, r0+1 (contiguous).
// Stream order A(r0),A(r0+1),B(r0),B(r0+1): two long contiguous segments
// (65.6KB + 32.8KB) per wave. x from LDS; h0 from L2.
__global__ __launch_bounds__(512, 8) void lstm_step_kernel(
    const float* __restrict__ x, const float* __restrict__ h0,
    const float* __restrict__ c0,
    const float* __restrict__ W_ih, const float* __restrict__ W_hh,
    const float* __restrict__ b_ih, const float* __restrict__ b_hh,
    float* __restrict__ h_out)
{
    __shared__ float4 xs[ND4];
    __shared__ float gate[4][4];

    const int tid = threadIdx.x;
    {
        const float4* __restrict__ x4 = (const float4*)x;
        for (int i = tid; i < ND4; i += 512) xs[i] = x4[i];
    }
    __syncthreads();

    const int w    = tid >> 6;   // wave 0..7
    const int lane = tid & 63;
    const int g    = w & 3;      // gate (i,f,g,o)
    const int p    = w >> 2;     // unit pair 0/1
    const int j0   = blockIdx.x * 4;
    const int u0   = 2 * p;                        // first unit of this wave
    const size_t r0 = (size_t)g * H + j0 + u0;     // first gate row

    float a0 = 0.0f, a1 = 0.0f;

    // ---- W_ih rows r0, r0+1: one contiguous 65.6 KB stream ----
    {
        const float4* __restrict__ A = (const float4*)(W_ih + r0 * D);
        #pragma unroll 8
        for (int it = 0; it < 32; ++it) {
            const int idx = it * 64 + lane;
            a0 += dot4(A[idx], xs[idx]);
        }
        if (lane == 0) a0 += dot4(A[2048], xs[2048]);
        #pragma unroll 8
        for (int it = 0; it < 32; ++it) {
            const int idx = it * 64 + lane;
            a1 += dot4(A[ND4 + idx], xs[idx]);
        }
        if (lane == 0) a1 += dot4(A[ND4 + 2048], xs[2048]);
    }
    // ---- W_hh rows r0, r0+1: one contiguous 32.8 KB stream; h0 via L2 ----
    {
        const float4* __restrict__ B = (const float4*)(W_hh + r0 * H);
        const float4* __restrict__ h4 = (const float4*)h0;
        #pragma unroll 8
        for (int it = 0; it < 16; ++it) {
            const int idx = it * 64 + lane;
            a0 += dot4(B[idx], h4[idx]);
        }
        #pragma unroll 8
        for (int it = 0; it < 16; ++it) {
            const int idx = it * 64 + lane;
            a1 += dot4(B[NH4 + idx], h4[idx]);
        }
    }

    a0 = wave_reduce(a0);
    a1 = wave_reduce(a1);
    if (lane == 0) {
        gate[g][u0]     = a0 + b_ih[r0]     + b_hh[r0];
        gate[g][u0 + 1] = a1 + b_ih[r0 + 1] + b_hh[r0 + 1];
    }
    __syncthreads();

    if (tid < 4) {
        const int j = j0 + tid;
        const float ig = sigmoidf_(gate[0][tid]);
        const float fg = sigmoidf_(gate[1][tid]);
        const float gg = tanhf(gate[2][tid]);
        const float og = sigmoidf_(gate[3][tid]);
        const float c  = fg * c0[j] + ig * gg;
        h_out[j] = og * tanhf(c);
    }
}

// 32 blocks x 64 threads: block r computes z[r] = relu(W1[r,:] @ h + b1[r])
__global__ __launch_bounds__(64) void mlp_z_kernel(
    const float* __restrict__ h,
    const float* __restrict__ W1, const float* __restrict__ b1,
    float* __restrict__ z)
{
    const int r    = blockIdx.x;
    const int lane = threadIdx.x;
    const float4* __restrict__ Wr = (const float4*)(W1 + (size_t)r * H);
    const float4* __restrict__ h4 = (const float4*)h;
    float acc = 0.0f;
    #pragma unroll 4
    for (int it = 0; it < 16; ++it) {
        const int idx = it * 64 + lane;
        acc += dot4(Wr[idx], h4[idx]);
    }
    acc = wave_reduce(acc);
    if (lane == 0)
        z[r] = fmaxf(acc + b1[r], 0.0f);
}

// 1 block: out = sigmoid(W2 @ z + b2), 130 outputs
__global__ __launch_bounds__(192) void mlp_out_kernel(
    const float* __restrict__ z,
    const float* __restrict__ W2, const float* __restrict__ b2,
    float* __restrict__ out)
{
    __shared__ float zs[MLP_HID];
    if (threadIdx.x < MLP_HID) zs[threadIdx.x] = z[threadIdx.x];
    __syncthreads();
    const int t = threadIdx.x;
    if (t < OUT_N) {
        float acc = b2[t];
        #pragma unroll
        for (int k = 0; k < MLP_HID; ++k)
            acc += W2[t * MLP_HID + k] * zs[k];
        out[t] = sigmoidf_(acc);
    }
}

extern "C" void kernel_launch(void* const* d_in, const int* in_sizes, int n_in,
                              void* d_out, int out_size, void* d_ws, size_t ws_size,
                              hipStream_t stream) {
    const float* x    = (const float*)d_in[0];
    const float* h0   = (const float*)d_in[1];
    const float* c0   = (const float*)d_in[2];
    const float* W_ih = (const float*)d_in[3];
    const float* W_hh = (const float*)d_in[4];
    const float* b_ih = (const float*)d_in[5];
    const float* b_hh = (const float*)d_in[6];
    const float* W1   = (const float*)d_in[7];
    const float* b1   = (const float*)d_in[8];
    const float* W2   = (const float*)d_in[9];
    const float* b2   = (const float*)d_in[10];
    float* out = (float*)d_out;

    // ws layout: [0, 16KB) h, [16KB, 16KB+128) z
    float* h_ws = (float*)d_ws;
    float* z_ws = (float*)((char*)d_ws + 16384);

    lstm_step_kernel<<<H / 4, 512, 0, stream>>>(x, h0, c0, W_ih, W_hh, b_ih, b_hh, h_ws);
    mlp_z_kernel<<<MLP_HID, 64, 0, stream>>>(h_ws, W1, b1, z_ws);
    mlp_out_kernel<<<1, 192, 0, stream>>>(z_ws, W2, b2, out);
}

// Round 8
// 149.136 us; speedup vs baseline: 1.0365x; 1.0365x over previous
//
#include <hip/hip_runtime.h>
#include <hip/hip_bf16.h>

#define D 8196
#define H 4096
#define MLP_HID 32
#define OUT_N 130
#define ND4 2049   // D/4 float4s per W_ih row
#define NH4 1024   // H/4 float4s per W_hh row

__device__ __forceinline__ float sigmoidf_(float v) {
    return 1.0f / (1.0f + expf(-v));
}

__device__ __forceinline__ float dot4(float4 a, float4 b) {
    return a.x * b.x + a.y * b.y + a.z * b.z + a.w * b.w;
}

__device__ __forceinline__ float wave_reduce(float acc) {
    #pragma unroll
    for (int off = 32; off > 0; off >>= 1)
        acc += __shfl_down(acc, off);
    return acc;
}

// 512 blocks x 512 threads (8 waves), 2 blocks/CU (grid == resident/… single
// round, LDS = 49.2 KB for x AND h0). Block owns units j0..j0+7. Wave w:
// gate g=w&3, quad p=w>>2 -> 4 CONTIGUOUS rows r0=g*H+j0+4p..+3.
// Inner loops issue ONLY weight loads to the global path (x, h0 both LDS) —
// no L2 loads stealing VMEM queue slots; per-wave contiguous streams are
// 131 KB (W_ih) + 65.6 KB (W_hh).
__global__ __launch_bounds__(512, 4) void lstm_step_kernel(
    const float* __restrict__ x, const float* __restrict__ h0,
    const float* __restrict__ c0,
    const float* __restrict__ W_ih, const float* __restrict__ W_hh,
    const float* __restrict__ b_ih, const float* __restrict__ b_hh,
    float* __restrict__ h_out)
{
    __shared__ float4 xs[ND4];
    __shared__ float4 hs[NH4];
    __shared__ float gate[4][8];

    const int tid = threadIdx.x;
    {
        const float4* __restrict__ x4 = (const float4*)x;
        const float4* __restrict__ h4 = (const float4*)h0;
        for (int i = tid; i < ND4; i += 512) xs[i] = x4[i];
        for (int i = tid; i < NH4; i += 512) hs[i] = h4[i];
    }
    __syncthreads();

    const int w    = tid >> 6;   // wave 0..7
    const int lane = tid & 63;
    const int g    = w & 3;      // gate (i,f,g,o)
    const int p    = w >> 2;     // row quad 0/1
    const int j0   = blockIdx.x * 8;
    const int u0   = 4 * p;                      // first unit of this wave
    const size_t r0 = (size_t)g * H + j0 + u0;   // first of 4 contiguous rows

    float acc[4];

    // ---- W_ih rows r0..r0+3: one contiguous 131 KB stream ----
    {
        const float4* __restrict__ A = (const float4*)(W_ih + r0 * D);
        #pragma unroll
        for (int rr = 0; rr < 4; ++rr) {
            const float4* __restrict__ Ar = A + (size_t)rr * ND4;
            float a = 0.0f;
            #pragma unroll 8
            for (int it = 0; it < 32; ++it) {
                const int idx = it * 64 + lane;
                a += dot4(Ar[idx], xs[idx]);
            }
            if (lane == 0) a += dot4(Ar[2048], xs[2048]);
            acc[rr] = a;
        }
    }
    // ---- W_hh rows r0..r0+3: one contiguous 65.6 KB stream ----
    {
        const float4* __restrict__ B = (const float4*)(W_hh + r0 * H);
        #pragma unroll
        for (int rr = 0; rr < 4; ++rr) {
            const float4* __restrict__ Br = B + (size_t)rr * NH4;
            float a = acc[rr];
            #pragma unroll 8
            for (int it = 0; it < 16; ++it) {
                const int idx = it * 64 + lane;
                a += dot4(Br[idx], hs[idx]);
            }
            acc[rr] = a;
        }
    }

    #pragma unroll
    for (int rr = 0; rr < 4; ++rr) {
        const float a = wave_reduce(acc[rr]);
        if (lane == 0)
            gate[g][u0 + rr] = a + b_ih[r0 + rr] + b_hh[r0 + rr];
    }
    __syncthreads();

    if (tid < 8) {
        const int j = j0 + tid;
        const float ig = sigmoidf_(gate[0][tid]);
        const float fg = sigmoidf_(gate[1][tid]);
        const float gg = tanhf(gate[2][tid]);
        const float og = sigmoidf_(gate[3][tid]);
        const float c  = fg * c0[j] + ig * gg;
        h_out[j] = og * tanhf(c);
    }
}

// 32 blocks x 64 threads: block r computes z[r] = relu(W1[r,:] @ h + b1[r])
__global__ __launch_bounds__(64) void mlp_z_kernel(
    const float* __restrict__ h,
    const float* __restrict__ W1, const float* __restrict__ b1,
    float* __restrict__ z)
{
    const int r    = blockIdx.x;
    const int lane = threadIdx.x;
    const float4* __restrict__ Wr = (const float4*)(W1 + (size_t)r * H);
    const float4* __restrict__ h4 = (const float4*)h;
    float acc = 0.0f;
    #pragma unroll 4
    for (int it = 0; it < 16; ++it) {
        const int idx = it * 64 + lane;
        acc += dot4(Wr[idx], h4[idx]);
    }
    acc = wave_reduce(acc);
    if (lane == 0)
        z[r] = fmaxf(acc + b1[r], 0.0f);
}

// 1 block: out = sigmoid(W2 @ z + b2), 130 outputs
__global__ __launch_bounds__(192) void mlp_out_kernel(
    const float* __restrict__ z,
    const float* __restrict__ W2, const float* __restrict__ b2,
    float* __restrict__ out)
{
    __shared__ float zs[MLP_HID];
    if (threadIdx.x < MLP_HID) zs[threadIdx.x] = z[threadIdx.x];
    __syncthreads();
    const int t = threadIdx.x;
    if (t < OUT_N) {
        float acc = b2[t];
        #pragma unroll
        for (int k = 0; k < MLP_HID; ++k)
            acc += W2[t * MLP_HID + k] * zs[k];
        out[t] = sigmoidf_(acc);
    }
}

extern "C" void kernel_launch(void* const* d_in, const int* in_sizes, int n_in,
                              void* d_out, int out_size, void* d_ws, size_t ws_size,
                              hipStream_t stream) {
    const float* x    = (const float*)d_in[0];
    const float* h0   = (const float*)d_in[1];
    const float* c0   = (const float*)d_in[2];
    const float* W_ih = (const float*)d_in[3];
    const float* W_hh = (const float*)d_in[4];
    const float* b_ih = (const float*)d_in[5];
    const float* b_hh = (const float*)d_in[6];
    const float* W1   = (const float*)d_in[7];
    const float* b1   = (const float*)d_in[8];
    const float* W2   = (const float*)d_in[9];
    const float* b2   = (const float*)d_in[10];
    float* out = (float*)d_out;

    // ws layout: [0, 16KB) h, [16KB, 16KB+128) z
    float* h_ws = (float*)d_ws;
    float* z_ws = (float*)((char*)d_ws + 16384);

    lstm_step_kernel<<<H / 8, 512, 0, stream>>>(x, h0, c0, W_ih, W_hh, b_ih, b_hh, h_ws);
    mlp_z_kernel<<<MLP_HID, 64, 0, stream>>>(h_ws, W1, b1, z_ws);
    mlp_out_kernel<<<1, 192, 0, stream>>>(z_ws, W2, b2, out);
}